// Round 2
// baseline (5476.151 us; speedup 1.0000x reference)
//
#include <hip/hip_runtime.h>
#include <cstdint>
#include <cstddef>

static constexpr int Nn = 8192;   // rows of X
static constexpr int Mm = 8192;   // rows of Y
static constexpr int Kd = 256;    // feature dim
static constexpr float LAM_F   = 10.0f;
static constexpr float INV_N_F = 1.0f / 8192.0f;

typedef _Float16 h16;
typedef _Float16 h16x4 __attribute__((ext_vector_type(4)));
typedef _Float16 f16x8 __attribute__((ext_vector_type(8)));
typedef float    f32x16 __attribute__((ext_vector_type(16)));

// ---------- load/store helpers (overloaded on storage type) ----------
__device__ __forceinline__ void load8(const h16* p, float* o) {
  uint4 q = *(const uint4*)p;               // 16B aligned in fast path
  const h16* h = (const h16*)&q;
#pragma unroll
  for (int i = 0; i < 8; ++i) o[i] = (float)h[i];
}
__device__ __forceinline__ void load8(const float* p, float* o) {
#pragma unroll
  for (int i = 0; i < 8; ++i) o[i] = p[i];  // fallback path
}
__device__ __forceinline__ void store4e(float* p, float a, float b, float c, float d) {
  p[0] = a; p[1] = b; p[2] = c; p[3] = d;
}

// ---------- setup: row norms, u=1, cost=0, t=0, counters=0, fp16 X,Y ----------
__global__ __launch_bounds__(256) void setup_kernel(
    const float* __restrict__ X, const float* __restrict__ Y,
    float* __restrict__ x2, float* __restrict__ y2,
    float* __restrict__ u, float* __restrict__ cost,
    h16* __restrict__ Xh, h16* __restrict__ Yh,
    float* __restrict__ t, unsigned* __restrict__ cnt) {
  const int gid  = blockIdx.x * blockDim.x + threadIdx.x;
  const int wid  = gid >> 6;          // 0..16383 : one wave per row
  const int lane = threadIdx.x & 63;
  const bool isX = wid < Nn;
  const int row  = isX ? wid : wid - Nn;
  const float4* rp = (const float4*)((isX ? X : Y) + (size_t)row * Kd);
  float4 q = rp[lane];                // 64 lanes x float4 = 256 floats
  // fp16 copy for the MFMA cost-matrix build
  h16x4 hq; hq[0] = (h16)q.x; hq[1] = (h16)q.y; hq[2] = (h16)q.z; hq[3] = (h16)q.w;
  *(h16x4*)((isX ? Xh : Yh) + (size_t)row * Kd + lane * 4) = hq;
  float s = q.x*q.x + q.y*q.y + q.z*q.z + q.w*q.w;
#pragma unroll
  for (int o = 32; o > 0; o >>= 1) s += __shfl_down(s, o);
  if (lane == 0) { if (isX) x2[row] = s; else y2[row] = s; }
  if (gid < Mm) { u[gid] = 1.0f; t[gid] = 0.0f; }   // g0 = 0 -> u0 = 1; t zeroed for atomics
  if (gid < 8)  cnt[gid] = 0u;
  if (gid == 0) cost[0] = 0.0f;
}

// ---------- build K = exp(-C/LAM) via MFMA f16, 128x128 tile ----------
__global__ __launch_bounds__(256) void build_e_mfma(
    const h16* __restrict__ Xh, const h16* __restrict__ Yh,
    const float* __restrict__ x2, const float* __restrict__ y2,
    h16* __restrict__ E) {
  __shared__ h16 smem[16384];         // 32 KB: A[0..8191], B[8192..16383]; epilogue reuses as 128x128 tile
  __shared__ float x2s[128], y2s[128];
  const int tid = threadIdx.x;
  const int i0 = blockIdx.y * 128, j0 = blockIdx.x * 128;
  if (tid < 128) x2s[tid] = x2[i0 + tid];
  else           y2s[tid - 128] = y2[j0 + tid - 128];

  f32x16 acc[2][2];
#pragma unroll
  for (int a = 0; a < 2; ++a)
#pragma unroll
    for (int b = 0; b < 2; ++b)
#pragma unroll
      for (int r = 0; r < 16; ++r) acc[a][b][r] = 0.0f;

  const int w = tid >> 6, lane = tid & 63;
  const int mt0 = (w >> 1) * 2, nt0 = (w & 1) * 2;   // wave quadrant: 2 m-tiles x 2 n-tiles of 32

  for (int kc = 0; kc < 4; ++kc) {                   // K = 256 in 4 chunks of 64
    __syncthreads();
#pragma unroll
    for (int p = 0; p < 4; ++p) {                    // stage 128 rows x 64 k (A and B)
      const int c  = p * 256 + tid;                  // 1024 16B-chunks each (8 chunks/row of 64 k)
      const int r  = c >> 3, k8 = c & 7;
      const int mt = r >> 5, m = r & 31, s = k8 >> 1, hf = k8 & 1;
      const int dst = ((mt * 4 + s) * 64 + m + 32 * hf) * 8;
      *(uint4*)(smem + dst)        = *(const uint4*)(Xh + (size_t)(i0 + r) * Kd + kc * 64 + k8 * 8);
      *(uint4*)(smem + 8192 + dst) = *(const uint4*)(Yh + (size_t)(j0 + r) * Kd + kc * 64 + k8 * 8);
    }
    __syncthreads();
#pragma unroll
    for (int s = 0; s < 4; ++s) {                    // 4 k-steps of 16
      f16x8 a0 = *(const f16x8*)(smem + (((mt0    ) * 4 + s) * 64 + lane) * 8);
      f16x8 a1 = *(const f16x8*)(smem + (((mt0 + 1) * 4 + s) * 64 + lane) * 8);
      f16x8 b0 = *(const f16x8*)(smem + 8192 + (((nt0    ) * 4 + s) * 64 + lane) * 8);
      f16x8 b1 = *(const f16x8*)(smem + 8192 + (((nt0 + 1) * 4 + s) * 64 + lane) * 8);
      acc[0][0] = __builtin_amdgcn_mfma_f32_32x32x16_f16(a0, b0, acc[0][0], 0, 0, 0);
      acc[0][1] = __builtin_amdgcn_mfma_f32_32x32x16_f16(a0, b1, acc[0][1], 0, 0, 0);
      acc[1][0] = __builtin_amdgcn_mfma_f32_32x32x16_f16(a1, b0, acc[1][0], 0, 0, 0);
      acc[1][1] = __builtin_amdgcn_mfma_f32_32x32x16_f16(a1, b1, acc[1][1], 0, 0, 0);
    }
  }

  __syncthreads();                                   // all waves done reading A/B
  const int mq = (w >> 1) * 64, nq = (w & 1) * 64;
#pragma unroll
  for (int ti = 0; ti < 2; ++ti)
#pragma unroll
    for (int tj = 0; tj < 2; ++tj) {
      const int colb = nq + tj * 32 + (lane & 31);
      const float yv = y2s[colb];
#pragma unroll
      for (int r = 0; r < 16; ++r) {
        // 32x32 C/D layout: col = lane&31, row = (r&3) + 8*(r>>2) + 4*(lane>>5)
        const int rowb = mq + ti * 32 + (r & 3) + 8 * (r >> 2) + 4 * (lane >> 5);
        float sq = x2s[rowb] + yv - 2.0f * acc[ti][tj][r];
        float cc = sqrtf(fmaxf(sq, 0.0f) + 1e-6f);
        smem[rowb * 128 + colb] = (h16)__expf(-0.1f * cc);
      }
    }
  __syncthreads();
#pragma unroll
  for (int p = 0; p < 8; ++p) {                      // coalesced 16B stores of the 128x128 tile
    const int c = p * 256 + tid;                     // 2048 chunks = 128 rows x 16 chunks
    const int r = c >> 4, k16 = c & 15;
    *(uint4*)(E + (size_t)(i0 + r) * Mm + j0 + k16 * 8) = *(const uint4*)(smem + r * 128 + k16 * 8);
  }
}

// ---------- fallback fp32 build (ws too small for fp16 E) ----------
template <typename ET>
__global__ __launch_bounds__(256) void build_e_f32(
    const float* __restrict__ X, const float* __restrict__ Y,
    const float* __restrict__ x2, const float* __restrict__ y2,
    ET* __restrict__ E) {
  __shared__ float As[64][66];
  __shared__ float Bs[64][66];
  const int tid = threadIdx.x;
  const int tx = tid & 15;
  const int ty = tid >> 4;
  const int i0 = blockIdx.y * 64;
  const int j0 = blockIdx.x * 64;
  float acc[4][4] = {};
  for (int k0 = 0; k0 < Kd; k0 += 64) {
    __syncthreads();
#pragma unroll
    for (int rep = 0; rep < 16; ++rep) {
      const int e = rep * 256 + tid;
      const int k = e & 63, i = e >> 6;
      As[k][i] = X[(size_t)(i0 + i) * Kd + k0 + k];
      Bs[k][i] = Y[(size_t)(j0 + i) * Kd + k0 + k];
    }
    __syncthreads();
    for (int k = 0; k < 64; ++k) {
      float a0 = As[k][ty*4+0], a1 = As[k][ty*4+1], a2 = As[k][ty*4+2], a3 = As[k][ty*4+3];
      float b0 = Bs[k][tx*4+0], b1 = Bs[k][tx*4+1], b2 = Bs[k][tx*4+2], b3 = Bs[k][tx*4+3];
      acc[0][0] += a0*b0; acc[0][1] += a0*b1; acc[0][2] += a0*b2; acc[0][3] += a0*b3;
      acc[1][0] += a1*b0; acc[1][1] += a1*b1; acc[1][2] += a1*b2; acc[1][3] += a1*b3;
      acc[2][0] += a2*b0; acc[2][1] += a2*b1; acc[2][2] += a2*b2; acc[2][3] += a2*b3;
      acc[3][0] += a3*b0; acc[3][1] += a3*b1; acc[3][2] += a3*b2; acc[3][3] += a3*b3;
    }
  }
  float xx[4], yy[4];
#pragma unroll
  for (int d = 0; d < 4; ++d) { xx[d] = x2[i0 + ty*4 + d]; yy[d] = y2[j0 + tx*4 + d]; }
#pragma unroll
  for (int di = 0; di < 4; ++di) {
    float e4[4];
#pragma unroll
    for (int dj = 0; dj < 4; ++dj) {
      float sq = xx[di] + yy[dj] - 2.0f * acc[di][dj];
      float c  = sqrtf(fmaxf(sq, 0.0f) + 1e-6f);
      e4[dj] = __expf(-c * 0.1f);
    }
    store4e(&E[(size_t)(i0 + ty*4 + di) * Mm + j0 + tx*4], e4[0], e4[1], e4[2], e4[3]);
  }
}

// ---------- FAST row pass: 2 rows per wave, deep load batches ----------
// v_{r} = (1/n) / sum_j E_rj u_j.  u (32 KB) shared by both rows -> halves
// the redundant L1 u-traffic; 16 E-loads + 8 u-loads issued per chunk
// before any use -> ~128 KB in flight per CU (Little's law >> L3 BW need).
__global__ __launch_bounds__(256) void row_pass2_kernel(
    const h16* __restrict__ E, const float* __restrict__ u, float* __restrict__ v) {
  const int wid  = (blockIdx.x * blockDim.x + threadIdx.x) >> 6;  // 0..4095
  const int lane = threadIdx.x & 63;
  const int r0   = wid * 2;
  const h16* row = E + (size_t)r0 * Mm;
  float s0 = 0.0f, s1 = 0.0f;
#pragma unroll 1
  for (int cc = 0; cc < 4; ++cc) {                   // 4 chunks of 2048 columns
    uint4  q0[4], q1[4];
    float4 ua[4], ub[4];
#pragma unroll
    for (int g = 0; g < 4; ++g) {                    // issue all loads first
      const int j8 = ((cc * 4 + g) * 64 + lane) * 8;
      q0[g] = *(const uint4*)(row + j8);
      q1[g] = *(const uint4*)(row + (size_t)Mm + j8);
      ua[g] = *(const float4*)(u + j8);
      ub[g] = *(const float4*)(u + j8 + 4);
    }
#pragma unroll
    for (int g = 0; g < 4; ++g) {
      const float uu[8] = {ua[g].x, ua[g].y, ua[g].z, ua[g].w,
                           ub[g].x, ub[g].y, ub[g].z, ub[g].w};
      const h16* h0 = (const h16*)&q0[g];
      const h16* h1 = (const h16*)&q1[g];
#pragma unroll
      for (int c = 0; c < 8; ++c) {
        s0 = fmaf((float)h0[c], uu[c], s0);
        s1 = fmaf((float)h1[c], uu[c], s1);
      }
    }
  }
#pragma unroll
  for (int o = 32; o > 0; o >>= 1) { s0 += __shfl_down(s0, o); s1 += __shfl_down(s1, o); }
  if (lane == 0) {
    float2 o2 = make_float2(INV_N_F / s0, INV_N_F / s1);
    *(float2*)(v + r0) = o2;
  }
}

// ---------- FAST col pass: atomic column sums + fused combine ----------
// t_j += sum_{i in 64-row chunk} E_ij v_i  via device-scope atomicAdd.
// Last block per 2048-column strip (syncthreads + threadfence + counter
// handshake) reads t via atomicExch (coherent point), writes u_j = (1/m)/t_j,
// leaves t=0 for the next iteration.  Kills the separate combine kernel.
__global__ __launch_bounds__(256) void col_pass_at_kernel(
    const h16* __restrict__ E, const float* __restrict__ v,
    float* __restrict__ t, float* __restrict__ u, unsigned* __restrict__ cnt) {
  const int c0 = blockIdx.x * 2048 + threadIdx.x * 8;
  const int r0 = blockIdx.y * 64;
  const h16* base = E + (size_t)r0 * Mm + c0;
  float acc[8] = {};
#pragma unroll 2
  for (int rb = 0; rb < 64; rb += 8) {               // batches of 8 rows, loads issued first
    uint4 q[8];
#pragma unroll
    for (int r = 0; r < 8; ++r) q[r] = *(const uint4*)(base + (size_t)(rb + r) * Mm);
#pragma unroll
    for (int r = 0; r < 8; ++r) {
      const float vr = v[r0 + rb + r];               // wave-uniform -> scalar load
      const h16* h = (const h16*)&q[r];
#pragma unroll
      for (int c = 0; c < 8; ++c) acc[c] = fmaf((float)h[c], vr, acc[c]);
    }
  }
#pragma unroll
  for (int c = 0; c < 8; ++c) atomicAdd(t + c0 + c, acc[c]);
  __threadfence();                                   // order this thread's atomics
  __syncthreads();                                   // ALL waves of this block done (drains vmcnt)
  __shared__ bool s_last;
  if (threadIdx.x == 0) {
    unsigned old = atomicAdd(cnt + blockIdx.x, 1u);  // never reset; 128 blocks/strip
    s_last = ((old & 127u) == 127u);
  }
  __syncthreads();
  if (s_last) {                                      // all 128 chunk-blocks of this strip done
#pragma unroll
    for (int c = 0; c < 8; ++c) {
      const float val = atomicExch(t + c0 + c, 0.0f);  // coherent read + re-zero for next iter
      u[c0 + c] = INV_N_F / val;
    }
  }
}

// ---------- fallback row pass (fp32 path) ----------
template <typename ET>
__global__ __launch_bounds__(256) void row_pass_kernel(
    const ET* __restrict__ E, const float* __restrict__ u, float* __restrict__ v) {
  const int wid  = (blockIdx.x * blockDim.x + threadIdx.x) >> 6;
  const int lane = threadIdx.x & 63;
  const ET* row = E + (size_t)wid * Mm;
  float s = 0.0f;
#pragma unroll 4
  for (int g = 0; g < 16; ++g) {
    const int j8 = (g * 64 + lane) * 8;
    float ev[8]; load8(row + j8, ev);
    const float4 u0 = *(const float4*)(u + j8);
    const float4 u1 = *(const float4*)(u + j8 + 4);
    s += ev[0]*u0.x + ev[1]*u0.y + ev[2]*u0.z + ev[3]*u0.w;
    s += ev[4]*u1.x + ev[5]*u1.y + ev[6]*u1.z + ev[7]*u1.w;
  }
#pragma unroll
  for (int o = 32; o > 0; o >>= 1) s += __shfl_down(s, o);
  if (lane == 0) v[wid] = INV_N_F / s;
}

// ---------- fallback col pass partials ----------
template <typename ET>
__global__ __launch_bounds__(256) void col_pass_kernel(
    const ET* __restrict__ E, const float* __restrict__ v, float* __restrict__ part) {
  const int c0 = blockIdx.x * 2048 + threadIdx.x * 8;
  const int r0 = blockIdx.y * 64;
  float acc[8] = {};
#pragma unroll 4
  for (int r = r0; r < r0 + 64; ++r) {
    const float vr = v[r];
    float ev[8]; load8(E + (size_t)r * Mm + c0, ev);
#pragma unroll
    for (int c = 0; c < 8; ++c) acc[c] += ev[c] * vr;
  }
  float* dst = part + (size_t)blockIdx.y * Mm + c0;
  *(float4*)dst       = make_float4(acc[0], acc[1], acc[2], acc[3]);
  *((float4*)dst + 1) = make_float4(acc[4], acc[5], acc[6], acc[7]);
}

// ---------- fallback combine ----------
__global__ __launch_bounds__(256) void combine_kernel(
    const float* __restrict__ part, float* __restrict__ u) {
  const int j = blockIdx.x * blockDim.x + threadIdx.x;
  float t = 0.0f;
#pragma unroll 8
  for (int c = 0; c < 128; ++c) t += part[(size_t)c * Mm + j];
  u[j] = INV_N_F / t;
}

// ---------- final: pi = v_i K_ij u_j ; cost = sum pi * (-LAM log K) ----------
template <typename ET>
__global__ __launch_bounds__(256) void final_pass_kernel(
    const ET* E, const float* __restrict__ v, const float* __restrict__ u,
    float* pi, float* cost) {            // E/pi may alias (fallback) -> no restrict
  const int wid  = (blockIdx.x * blockDim.x + threadIdx.x) >> 6;
  const int lane = threadIdx.x & 63;
  const ET* row = E + (size_t)wid * Mm;
  float* prow = pi + (size_t)wid * Mm;
  const float vi = v[wid];
  float csum = 0.0f;
  for (int g = 0; g < 16; ++g) {
    const int j8 = (g * 64 + lane) * 8;
    float ev[8]; load8(row + j8, ev);
#pragma unroll
    for (int c = 0; c < 8; ++c) {
      const float uu  = u[j8 + c];
      const float p   = vi * ev[c] * uu;
      const float Cij = -LAM_F * __logf(ev[c]);
      prow[j8 + c] = p;
      csum += p * Cij;
    }
  }
#pragma unroll
  for (int o = 32; o > 0; o >>= 1) csum += __shfl_down(csum, o);
  if (lane == 0) atomicAdd(cost, csum);
}

// ---------- host ----------
extern "C" void kernel_launch(void* const* d_in, const int* in_sizes, int n_in,
                              void* d_out, int out_size, void* d_ws, size_t ws_size,
                              hipStream_t stream) {
  const float* X = (const float*)d_in[0];
  const float* Y = (const float*)d_in[1];
  float* out  = (float*)d_out;
  float* cost = out;
  float* pi   = out + 1;

  char*  ws   = (char*)d_ws;
  float* x2   = (float*)ws;
  float* y2   = x2 + Nn;
  float* u    = y2 + Mm;
  float* v    = u + Mm;
  float* part = v + Nn;                                   // 128 x 8192 f32 = 4 MB (fallback only)
  float*    t   = part;                                   // fast path: atomic col sums (reuses part)
  unsigned* cnt = (unsigned*)(part + Mm);                 // fast path: 4 strip counters
  const size_t small_bytes = (size_t)(4 * 8192 + 128 * 8192) * sizeof(float);
  const size_t e_off = (small_bytes + 255) & ~(size_t)255;
  const bool fast = ws_size >= e_off + (size_t)Nn * Mm * sizeof(h16) + 256;

  // fp16 X/Y copies parked inside the (not-yet-written) pi output region
  h16* Xh = (h16*)(((uintptr_t)pi + 15) & ~(uintptr_t)15);
  h16* Yh = Xh + (size_t)Nn * Kd;

  setup_kernel<<<4096, 256, 0, stream>>>(X, Y, x2, y2, u, cost, Xh, Yh, t, cnt);

  if (fast) {
    h16* E = (h16*)(ws + e_off);                          // fp16 K in workspace (128 MB, L3-resident)
    build_e_mfma<<<dim3(64, 64), 256, 0, stream>>>(Xh, Yh, x2, y2, E);
    for (int it = 0; it < 50; ++it) {
      row_pass2_kernel<<<1024, 256, 0, stream>>>(E, u, v);
      col_pass_at_kernel<<<dim3(4, 128), 256, 0, stream>>>(E, v, t, u, cnt);
    }
    final_pass_kernel<h16><<<2048, 256, 0, stream>>>(E, v, u, pi, cost);
  } else {
    float* E = pi;                                        // fallback: fp32 K parked in pi slot
    build_e_f32<float><<<dim3(128, 128), 256, 0, stream>>>(X, Y, x2, y2, E);
    for (int it = 0; it < 50; ++it) {
      row_pass_kernel<float><<<2048, 256, 0, stream>>>(E, u, v);
      col_pass_kernel<float><<<dim3(4, 128), 256, 0, stream>>>(E, v, part);
      combine_kernel<<<32, 256, 0, stream>>>(part, u);
    }
    final_pass_kernel<float><<<2048, 256, 0, stream>>>(E, v, u, pi, cost);  // in-place
  }
}

// Round 3
// 2957.144 us; speedup vs baseline: 1.8518x; 1.8518x over previous
//
#include <hip/hip_runtime.h>
#include <cstdint>
#include <cstddef>

static constexpr int Nn = 8192;   // rows of X
static constexpr int Mm = 8192;   // rows of Y
static constexpr int Kd = 256;    // feature dim
static constexpr float LAM_F   = 10.0f;
static constexpr float INV_N_F = 1.0f / 8192.0f;

typedef _Float16 h16;
typedef _Float16 h16x4 __attribute__((ext_vector_type(4)));
typedef _Float16 f16x8 __attribute__((ext_vector_type(8)));
typedef float    f32x16 __attribute__((ext_vector_type(16)));

// ---------- load/store helpers (overloaded on storage type) ----------
__device__ __forceinline__ void load8(const h16* p, float* o) {
  uint4 q = *(const uint4*)p;               // 16B aligned in fast path
  const h16* h = (const h16*)&q;
#pragma unroll
  for (int i = 0; i < 8; ++i) o[i] = (float)h[i];
}
__device__ __forceinline__ void load8(const float* p, float* o) {
#pragma unroll
  for (int i = 0; i < 8; ++i) o[i] = p[i];  // fallback path
}
__device__ __forceinline__ void store4e(float* p, float a, float b, float c, float d) {
  p[0] = a; p[1] = b; p[2] = c; p[3] = d;
}

// ---------- setup: row norms, u=1, cost=0, fp16 copies of X,Y ----------
__global__ __launch_bounds__(256) void setup_kernel(
    const float* __restrict__ X, const float* __restrict__ Y,
    float* __restrict__ x2, float* __restrict__ y2,
    float* __restrict__ u, float* __restrict__ cost,
    h16* __restrict__ Xh, h16* __restrict__ Yh) {
  const int gid  = blockIdx.x * blockDim.x + threadIdx.x;
  const int wid  = gid >> 6;          // 0..16383 : one wave per row
  const int lane = threadIdx.x & 63;
  const bool isX = wid < Nn;
  const int row  = isX ? wid : wid - Nn;
  const float4* rp = (const float4*)((isX ? X : Y) + (size_t)row * Kd);
  float4 q = rp[lane];                // 64 lanes x float4 = 256 floats
  // fp16 copy for the MFMA cost-matrix build
  h16x4 hq; hq[0] = (h16)q.x; hq[1] = (h16)q.y; hq[2] = (h16)q.z; hq[3] = (h16)q.w;
  *(h16x4*)((isX ? Xh : Yh) + (size_t)row * Kd + lane * 4) = hq;
  float s = q.x*q.x + q.y*q.y + q.z*q.z + q.w*q.w;
#pragma unroll
  for (int o = 32; o > 0; o >>= 1) s += __shfl_down(s, o);
  if (lane == 0) { if (isX) x2[row] = s; else y2[row] = s; }
  if (gid < Mm) u[gid] = 1.0f;        // g0 = 0  ->  u0 = 1
  if (gid == 0) cost[0] = 0.0f;
}

// ---------- build K = exp(-C/LAM) via MFMA f16, 128x128 tile ----------
__global__ __launch_bounds__(256) void build_e_mfma(
    const h16* __restrict__ Xh, const h16* __restrict__ Yh,
    const float* __restrict__ x2, const float* __restrict__ y2,
    h16* __restrict__ E) {
  __shared__ h16 smem[16384];         // 32 KB: A[0..8191], B[8192..16383]; epilogue reuses as 128x128 tile
  __shared__ float x2s[128], y2s[128];
  const int tid = threadIdx.x;
  const int i0 = blockIdx.y * 128, j0 = blockIdx.x * 128;
  if (tid < 128) x2s[tid] = x2[i0 + tid];
  else           y2s[tid - 128] = y2[j0 + tid - 128];

  f32x16 acc[2][2];
#pragma unroll
  for (int a = 0; a < 2; ++a)
#pragma unroll
    for (int b = 0; b < 2; ++b)
#pragma unroll
      for (int r = 0; r < 16; ++r) acc[a][b][r] = 0.0f;

  const int w = tid >> 6, lane = tid & 63;
  const int mt0 = (w >> 1) * 2, nt0 = (w & 1) * 2;   // wave quadrant: 2 m-tiles x 2 n-tiles of 32

  for (int kc = 0; kc < 4; ++kc) {                   // K = 256 in 4 chunks of 64
    __syncthreads();
#pragma unroll
    for (int p = 0; p < 4; ++p) {                    // stage 128 rows x 64 k (A and B)
      const int c  = p * 256 + tid;                  // 1024 16B-chunks each (8 chunks/row of 64 k)
      const int r  = c >> 3, k8 = c & 7;
      const int mt = r >> 5, m = r & 31, s = k8 >> 1, hf = k8 & 1;
      const int dst = ((mt * 4 + s) * 64 + m + 32 * hf) * 8;
      *(uint4*)(smem + dst)        = *(const uint4*)(Xh + (size_t)(i0 + r) * Kd + kc * 64 + k8 * 8);
      *(uint4*)(smem + 8192 + dst) = *(const uint4*)(Yh + (size_t)(j0 + r) * Kd + kc * 64 + k8 * 8);
    }
    __syncthreads();
#pragma unroll
    for (int s = 0; s < 4; ++s) {                    // 4 k-steps of 16
      f16x8 a0 = *(const f16x8*)(smem + (((mt0    ) * 4 + s) * 64 + lane) * 8);
      f16x8 a1 = *(const f16x8*)(smem + (((mt0 + 1) * 4 + s) * 64 + lane) * 8);
      f16x8 b0 = *(const f16x8*)(smem + 8192 + (((nt0    ) * 4 + s) * 64 + lane) * 8);
      f16x8 b1 = *(const f16x8*)(smem + 8192 + (((nt0 + 1) * 4 + s) * 64 + lane) * 8);
      acc[0][0] = __builtin_amdgcn_mfma_f32_32x32x16_f16(a0, b0, acc[0][0], 0, 0, 0);
      acc[0][1] = __builtin_amdgcn_mfma_f32_32x32x16_f16(a0, b1, acc[0][1], 0, 0, 0);
      acc[1][0] = __builtin_amdgcn_mfma_f32_32x32x16_f16(a1, b0, acc[1][0], 0, 0, 0);
      acc[1][1] = __builtin_amdgcn_mfma_f32_32x32x16_f16(a1, b1, acc[1][1], 0, 0, 0);
    }
  }

  __syncthreads();                                   // all waves done reading A/B
  const int mq = (w >> 1) * 64, nq = (w & 1) * 64;
#pragma unroll
  for (int ti = 0; ti < 2; ++ti)
#pragma unroll
    for (int tj = 0; tj < 2; ++tj) {
      const int colb = nq + tj * 32 + (lane & 31);
      const float yv = y2s[colb];
#pragma unroll
      for (int r = 0; r < 16; ++r) {
        // 32x32 C/D layout: col = lane&31, row = (r&3) + 8*(r>>2) + 4*(lane>>5)
        const int rowb = mq + ti * 32 + (r & 3) + 8 * (r >> 2) + 4 * (lane >> 5);
        float sq = x2s[rowb] + yv - 2.0f * acc[ti][tj][r];
        float cc = sqrtf(fmaxf(sq, 0.0f) + 1e-6f);
        smem[rowb * 128 + colb] = (h16)__expf(-0.1f * cc);
      }
    }
  __syncthreads();
#pragma unroll
  for (int p = 0; p < 8; ++p) {                      // coalesced 16B stores of the 128x128 tile
    const int c = p * 256 + tid;                     // 2048 chunks = 128 rows x 16 chunks
    const int r = c >> 4, k16 = c & 15;
    *(uint4*)(E + (size_t)(i0 + r) * Mm + j0 + k16 * 8) = *(const uint4*)(smem + r * 128 + k16 * 8);
  }
}

// ---------- fallback fp32 build (ws too small for fp16 E) ----------
template <typename ET>
__global__ __launch_bounds__(256) void build_e_f32(
    const float* __restrict__ X, const float* __restrict__ Y,
    const float* __restrict__ x2, const float* __restrict__ y2,
    ET* __restrict__ E) {
  __shared__ float As[64][66];
  __shared__ float Bs[64][66];
  const int tid = threadIdx.x;
  const int tx = tid & 15;
  const int ty = tid >> 4;
  const int i0 = blockIdx.y * 64;
  const int j0 = blockIdx.x * 64;
  float acc[4][4] = {};
  for (int k0 = 0; k0 < Kd; k0 += 64) {
    __syncthreads();
#pragma unroll
    for (int rep = 0; rep < 16; ++rep) {
      const int e = rep * 256 + tid;
      const int k = e & 63, i = e >> 6;
      As[k][i] = X[(size_t)(i0 + i) * Kd + k0 + k];
      Bs[k][i] = Y[(size_t)(j0 + i) * Kd + k0 + k];
    }
    __syncthreads();
    for (int k = 0; k < 64; ++k) {
      float a0 = As[k][ty*4+0], a1 = As[k][ty*4+1], a2 = As[k][ty*4+2], a3 = As[k][ty*4+3];
      float b0 = Bs[k][tx*4+0], b1 = Bs[k][tx*4+1], b2 = Bs[k][tx*4+2], b3 = Bs[k][tx*4+3];
      acc[0][0] += a0*b0; acc[0][1] += a0*b1; acc[0][2] += a0*b2; acc[0][3] += a0*b3;
      acc[1][0] += a1*b0; acc[1][1] += a1*b1; acc[1][2] += a1*b2; acc[1][3] += a1*b3;
      acc[2][0] += a2*b0; acc[2][1] += a2*b1; acc[2][2] += a2*b2; acc[2][3] += a2*b3;
      acc[3][0] += a3*b0; acc[3][1] += a3*b1; acc[3][2] += a3*b2; acc[3][3] += a3*b3;
    }
  }
  float xx[4], yy[4];
#pragma unroll
  for (int d = 0; d < 4; ++d) { xx[d] = x2[i0 + ty*4 + d]; yy[d] = y2[j0 + tx*4 + d]; }
#pragma unroll
  for (int di = 0; di < 4; ++di) {
    float e4[4];
#pragma unroll
    for (int dj = 0; dj < 4; ++dj) {
      float sq = xx[di] + yy[dj] - 2.0f * acc[di][dj];
      float c  = sqrtf(fmaxf(sq, 0.0f) + 1e-6f);
      e4[dj] = __expf(-c * 0.1f);
    }
    store4e(&E[(size_t)(i0 + ty*4 + di) * Mm + j0 + tx*4], e4[0], e4[1], e4[2], e4[3]);
  }
}

// ---------- FAST row pass: 2 rows per wave, 16-deep load batches ----------
// v_r = (1/n) / sum_j E_rj u_j.  u (32 KB) shared by both rows -> halves the
// redundant u L1 traffic; 8 E-loads + 8 u-loads issued before any consume.
__global__ __launch_bounds__(256) void row_pass2_kernel(
    const h16* __restrict__ E, const float* __restrict__ u, float* __restrict__ v) {
  const int wid  = (blockIdx.x * blockDim.x + threadIdx.x) >> 6;  // 0..4095
  const int lane = threadIdx.x & 63;
  const int r0   = wid * 2;
  const h16* row = E + (size_t)r0 * Mm;
  float s0 = 0.0f, s1 = 0.0f;
#pragma unroll 1
  for (int cc = 0; cc < 4; ++cc) {                   // 4 chunks of 2048 columns
    uint4  q0[4], q1[4];
    float4 ua[4], ub[4];
#pragma unroll
    for (int g = 0; g < 4; ++g) {                    // issue all 16 loads first
      const int j8 = ((cc * 4 + g) * 64 + lane) * 8;
      q0[g] = *(const uint4*)(row + j8);
      q1[g] = *(const uint4*)(row + (size_t)Mm + j8);
      ua[g] = *(const float4*)(u + j8);
      ub[g] = *(const float4*)(u + j8 + 4);
    }
#pragma unroll
    for (int g = 0; g < 4; ++g) {
      const float uu[8] = {ua[g].x, ua[g].y, ua[g].z, ua[g].w,
                           ub[g].x, ub[g].y, ub[g].z, ub[g].w};
      const h16* h0 = (const h16*)&q0[g];
      const h16* h1 = (const h16*)&q1[g];
#pragma unroll
      for (int c = 0; c < 8; ++c) {
        s0 = fmaf((float)h0[c], uu[c], s0);
        s1 = fmaf((float)h1[c], uu[c], s1);
      }
    }
  }
#pragma unroll
  for (int o = 32; o > 0; o >>= 1) { s0 += __shfl_down(s0, o); s1 += __shfl_down(s1, o); }
  if (lane == 0) {
    float2 o2 = make_float2(INV_N_F / s0, INV_N_F / s1);
    *(float2*)(v + r0) = o2;
  }
}

// ---------- col pass partials, 8-deep load batches (NO atomics) ----------
// part[chunk][j] = sum_{i in 64-row chunk} E_ij v_i ; deterministic stores.
template <typename ET>
__global__ __launch_bounds__(256) void col_pass_kernel(
    const ET* __restrict__ E, const float* __restrict__ v, float* __restrict__ part) {
  const int c0 = blockIdx.x * 2048 + threadIdx.x * 8;
  const int r0 = blockIdx.y * 64;
  const ET* base = E + (size_t)r0 * Mm + c0;
  float acc[8] = {};
#pragma unroll 2
  for (int rb = 0; rb < 64; rb += 8) {               // batches of 8 rows, loads issued first
    float ev[8][8];
#pragma unroll
    for (int r = 0; r < 8; ++r) load8(base + (size_t)(rb + r) * Mm, ev[r]);
#pragma unroll
    for (int r = 0; r < 8; ++r) {
      const float vr = v[r0 + rb + r];               // wave-uniform -> scalar load
#pragma unroll
      for (int c = 0; c < 8; ++c) acc[c] = fmaf(ev[r][c], vr, acc[c]);
    }
  }
  float* dst = part + (size_t)blockIdx.y * Mm + c0;
  *(float4*)dst       = make_float4(acc[0], acc[1], acc[2], acc[3]);
  *((float4*)dst + 1) = make_float4(acc[4], acc[5], acc[6], acc[7]);
}

// ---------- combine: u_j = (1/m) / sum_chunks part ----------
__global__ __launch_bounds__(256) void combine_kernel(
    const float* __restrict__ part, float* __restrict__ u) {
  const int j = blockIdx.x * blockDim.x + threadIdx.x;
  float t = 0.0f;
#pragma unroll 8
  for (int c = 0; c < 128; ++c) t += part[(size_t)c * Mm + j];
  u[j] = INV_N_F / t;
}

// ---------- fallback row pass (fp32 path) ----------
template <typename ET>
__global__ __launch_bounds__(256) void row_pass_kernel(
    const ET* __restrict__ E, const float* __restrict__ u, float* __restrict__ v) {
  const int wid  = (blockIdx.x * blockDim.x + threadIdx.x) >> 6;
  const int lane = threadIdx.x & 63;
  const ET* row = E + (size_t)wid * Mm;
  float s = 0.0f;
#pragma unroll 4
  for (int g = 0; g < 16; ++g) {
    const int j8 = (g * 64 + lane) * 8;
    float ev[8]; load8(row + j8, ev);
    const float4 u0 = *(const float4*)(u + j8);
    const float4 u1 = *(const float4*)(u + j8 + 4);
    s += ev[0]*u0.x + ev[1]*u0.y + ev[2]*u0.z + ev[3]*u0.w;
    s += ev[4]*u1.x + ev[5]*u1.y + ev[6]*u1.z + ev[7]*u1.w;
  }
#pragma unroll
  for (int o = 32; o > 0; o >>= 1) s += __shfl_down(s, o);
  if (lane == 0) v[wid] = INV_N_F / s;
}

// ---------- final: pi = v_i K_ij u_j ; cost = sum pi * (-LAM log K) ----------
template <typename ET>
__global__ __launch_bounds__(256) void final_pass_kernel(
    const ET* E, const float* __restrict__ v, const float* __restrict__ u,
    float* pi, float* cost) {            // E/pi may alias (fallback) -> no restrict
  const int wid  = (blockIdx.x * blockDim.x + threadIdx.x) >> 6;
  const int lane = threadIdx.x & 63;
  const ET* row = E + (size_t)wid * Mm;
  float* prow = pi + (size_t)wid * Mm;
  const float vi = v[wid];
  float csum = 0.0f;
  for (int g = 0; g < 16; ++g) {
    const int j8 = (g * 64 + lane) * 8;
    float ev[8]; load8(row + j8, ev);
#pragma unroll
    for (int c = 0; c < 8; ++c) {
      const float uu  = u[j8 + c];
      const float p   = vi * ev[c] * uu;
      const float Cij = -LAM_F * __logf(ev[c]);
      prow[j8 + c] = p;
      csum += p * Cij;
    }
  }
#pragma unroll
  for (int o = 32; o > 0; o >>= 1) csum += __shfl_down(csum, o);
  if (lane == 0) atomicAdd(cost, csum);
}

// ---------- host ----------
extern "C" void kernel_launch(void* const* d_in, const int* in_sizes, int n_in,
                              void* d_out, int out_size, void* d_ws, size_t ws_size,
                              hipStream_t stream) {
  const float* X = (const float*)d_in[0];
  const float* Y = (const float*)d_in[1];
  float* out  = (float*)d_out;
  float* cost = out;
  float* pi   = out + 1;

  char*  ws   = (char*)d_ws;
  float* x2   = (float*)ws;
  float* y2   = x2 + Nn;
  float* u    = y2 + Mm;
  float* v    = u + Mm;
  float* part = v + Nn;                                   // 128 x 8192 f32 = 4 MB
  const size_t small_bytes = (size_t)(4 * 8192 + 128 * 8192) * sizeof(float);
  const size_t e_off = (small_bytes + 255) & ~(size_t)255;
  const bool fast = ws_size >= e_off + (size_t)Nn * Mm * sizeof(h16) + 256;

  // fp16 X/Y copies parked inside the (not-yet-written) pi output region
  h16* Xh = (h16*)(((uintptr_t)pi + 15) & ~(uintptr_t)15);
  h16* Yh = Xh + (size_t)Nn * Kd;

  setup_kernel<<<4096, 256, 0, stream>>>(X, Y, x2, y2, u, cost, Xh, Yh);

  if (fast) {
    h16* E = (h16*)(ws + e_off);                          // fp16 K in workspace (128 MB, L3-resident)
    build_e_mfma<<<dim3(64, 64), 256, 0, stream>>>(Xh, Yh, x2, y2, E);
    for (int it = 0; it < 50; ++it) {
      row_pass2_kernel<<<1024, 256, 0, stream>>>(E, u, v);
      col_pass_kernel<h16><<<dim3(4, 128), 256, 0, stream>>>(E, v, part);
      combine_kernel<<<32, 256, 0, stream>>>(part, u);
    }
    final_pass_kernel<h16><<<2048, 256, 0, stream>>>(E, v, u, pi, cost);
  } else {
    float* E = pi;                                        // fallback: fp32 K parked in pi slot
    build_e_f32<float><<<dim3(128, 128), 256, 0, stream>>>(X, Y, x2, y2, E);
    for (int it = 0; it < 50; ++it) {
      row_pass_kernel<float><<<2048, 256, 0, stream>>>(E, u, v);
      col_pass_kernel<float><<<dim3(4, 128), 256, 0, stream>>>(E, v, part);
      combine_kernel<<<32, 256, 0, stream>>>(part, u);
    }
    final_pass_kernel<float><<<2048, 256, 0, stream>>>(E, v, u, pi, cost);  // in-place
  }
}

// Round 5
// 2219.893 us; speedup vs baseline: 2.4669x; 1.3321x over previous
//
#include <hip/hip_runtime.h>
#include <cstdint>
#include <cstddef>

static constexpr int Nn = 8192;   // rows of X
static constexpr int Mm = 8192;   // rows of Y
static constexpr int Kd = 256;    // feature dim
static constexpr float LAM_F   = 10.0f;
static constexpr float INV_N_F = 1.0f / 8192.0f;

typedef _Float16 h16;
typedef _Float16 h16x4 __attribute__((ext_vector_type(4)));
typedef _Float16 f16x8 __attribute__((ext_vector_type(8)));
typedef float    f32x16 __attribute__((ext_vector_type(16)));

// ---------- fp8 e4m3 helpers (HW cvt on gfx950; manual RNE fallback) ----------
__device__ __forceinline__ float dec1_fp8(uint32_t b) {      // fallback decode (positive, finite)
  uint32_t e = (b >> 3) & 15u, m = b & 7u;
  float n = __uint_as_float(((e + 120u) << 23) | (m << 20)); // normal
  float s = (float)m * 0.001953125f;                         // subnormal: m * 2^-9
  return e ? n : s;
}
__device__ __forceinline__ void cvt4_fp8(uint32_t w, float* o) {
#if __has_builtin(__builtin_amdgcn_cvt_pk_f32_fp8)
  auto lo = __builtin_amdgcn_cvt_pk_f32_fp8(w, false);
  auto hi = __builtin_amdgcn_cvt_pk_f32_fp8(w, true);
  o[0] = lo[0]; o[1] = lo[1]; o[2] = hi[0]; o[3] = hi[1];
#else
  o[0] = dec1_fp8(w & 255u); o[1] = dec1_fp8((w >> 8) & 255u);
  o[2] = dec1_fp8((w >> 16) & 255u); o[3] = dec1_fp8(w >> 24);
#endif
}
__device__ __forceinline__ uint8_t enc1_fp8(float x) {       // x in (0,1]
#if __has_builtin(__builtin_amdgcn_cvt_pk_fp8_f32)
  return (uint8_t)(__builtin_amdgcn_cvt_pk_fp8_f32(x, x, 0, false) & 0xff);
#else
  uint32_t b = __float_as_uint(x);
  int e = (int)((b >> 23) & 255) - 127;
  uint32_t m = b & 0x7fffffu;
  if (e < -9) return 0;
  if (e >= -6) {                                             // normal, RNE on 3-bit mantissa
    uint32_t keep = m >> 20, rest = m & 0xfffffu;
    if (rest > 0x80000u || (rest == 0x80000u && (keep & 1u))) keep++;
    return (uint8_t)(((uint32_t)(e + 7) << 3) + keep);       // carry rolls into exponent
  }
  return (uint8_t)(int)(x * 512.0f + 0.5f);                  // subnormal
#endif
}

// ---------- load helpers for fp32 fallback path ----------
__device__ __forceinline__ void load8(const float* p, float* o) {
#pragma unroll
  for (int i = 0; i < 8; ++i) o[i] = p[i];
}
__device__ __forceinline__ void store4e(float* p, float a, float b, float c, float d) {
  p[0] = a; p[1] = b; p[2] = c; p[3] = d;
}

// ---------- setup: row norms, u=1, cost=0, fp16 copies of X,Y ----------
__global__ __launch_bounds__(256) void setup_kernel(
    const float* __restrict__ X, const float* __restrict__ Y,
    float* __restrict__ x2, float* __restrict__ y2,
    float* __restrict__ u, float* __restrict__ cost,
    h16* __restrict__ Xh, h16* __restrict__ Yh) {
  const int gid  = blockIdx.x * blockDim.x + threadIdx.x;
  const int wid  = gid >> 6;          // 0..16383 : one wave per row
  const int lane = threadIdx.x & 63;
  const bool isX = wid < Nn;
  const int row  = isX ? wid : wid - Nn;
  const float4* rp = (const float4*)((isX ? X : Y) + (size_t)row * Kd);
  float4 q = rp[lane];                // 64 lanes x float4 = 256 floats
  h16x4 hq; hq[0] = (h16)q.x; hq[1] = (h16)q.y; hq[2] = (h16)q.z; hq[3] = (h16)q.w;
  *(h16x4*)((isX ? Xh : Yh) + (size_t)row * Kd + lane * 4) = hq;
  float s = q.x*q.x + q.y*q.y + q.z*q.z + q.w*q.w;
#pragma unroll
  for (int o = 32; o > 0; o >>= 1) s += __shfl_down(s, o);
  if (lane == 0) { if (isX) x2[row] = s; else y2[row] = s; }
  if (gid < Mm) u[gid] = 1.0f;        // g0 = 0  ->  u0 = 1
  if (gid == 0) cost[0] = 0.0f;
}

// ---------- build K = exp(-C/LAM) as fp8 e4m3 via MFMA f16, 128x128 tile ----------
__global__ __launch_bounds__(256) void build_e8_mfma(
    const h16* __restrict__ Xh, const h16* __restrict__ Yh,
    const float* __restrict__ x2, const float* __restrict__ y2,
    uint8_t* __restrict__ E8) {
  __shared__ h16 smem[16384];         // 32 KB: A/B staging; epilogue reuses first 16 KB as fp8 tile
  __shared__ float x2s[128], y2s[128];
  const int tid = threadIdx.x;
  const int i0 = blockIdx.y * 128, j0 = blockIdx.x * 128;
  if (tid < 128) x2s[tid] = x2[i0 + tid];
  else           y2s[tid - 128] = y2[j0 + tid - 128];

  f32x16 acc[2][2];
#pragma unroll
  for (int a = 0; a < 2; ++a)
#pragma unroll
    for (int b = 0; b < 2; ++b)
#pragma unroll
      for (int r = 0; r < 16; ++r) acc[a][b][r] = 0.0f;

  const int w = tid >> 6, lane = tid & 63;
  const int mt0 = (w >> 1) * 2, nt0 = (w & 1) * 2;

  for (int kc = 0; kc < 4; ++kc) {                   // K = 256 in 4 chunks of 64
    __syncthreads();
#pragma unroll
    for (int p = 0; p < 4; ++p) {                    // stage 128 rows x 64 k (A and B)
      const int c  = p * 256 + tid;
      const int r  = c >> 3, k8 = c & 7;
      const int mt = r >> 5, m = r & 31, s = k8 >> 1, hf = k8 & 1;
      const int dst = ((mt * 4 + s) * 64 + m + 32 * hf) * 8;
      *(uint4*)(smem + dst)        = *(const uint4*)(Xh + (size_t)(i0 + r) * Kd + kc * 64 + k8 * 8);
      *(uint4*)(smem + 8192 + dst) = *(const uint4*)(Yh + (size_t)(j0 + r) * Kd + kc * 64 + k8 * 8);
    }
    __syncthreads();
#pragma unroll
    for (int s = 0; s < 4; ++s) {                    // 4 k-steps of 16
      f16x8 a0 = *(const f16x8*)(smem + (((mt0    ) * 4 + s) * 64 + lane) * 8);
      f16x8 a1 = *(const f16x8*)(smem + (((mt0 + 1) * 4 + s) * 64 + lane) * 8);
      f16x8 b0 = *(const f16x8*)(smem + 8192 + (((nt0    ) * 4 + s) * 64 + lane) * 8);
      f16x8 b1 = *(const f16x8*)(smem + 8192 + (((nt0 + 1) * 4 + s) * 64 + lane) * 8);
      acc[0][0] = __builtin_amdgcn_mfma_f32_32x32x16_f16(a0, b0, acc[0][0], 0, 0, 0);
      acc[0][1] = __builtin_amdgcn_mfma_f32_32x32x16_f16(a0, b1, acc[0][1], 0, 0, 0);
      acc[1][0] = __builtin_amdgcn_mfma_f32_32x32x16_f16(a1, b0, acc[1][0], 0, 0, 0);
      acc[1][1] = __builtin_amdgcn_mfma_f32_32x32x16_f16(a1, b1, acc[1][1], 0, 0, 0);
    }
  }

  __syncthreads();                                   // all waves done reading A/B
  uint8_t* tile8 = (uint8_t*)smem;                   // 128x128 fp8 tile (16 KB)
  const int mq = (w >> 1) * 64, nq = (w & 1) * 64;
#pragma unroll
  for (int ti = 0; ti < 2; ++ti)
#pragma unroll
    for (int tj = 0; tj < 2; ++tj) {
      const int colb = nq + tj * 32 + (lane & 31);
      const float yv = y2s[colb];
#pragma unroll
      for (int r = 0; r < 16; ++r) {
        // 32x32 C/D layout: col = lane&31, row = (r&3) + 8*(r>>2) + 4*(lane>>5)
        const int rowb = mq + ti * 32 + (r & 3) + 8 * (r >> 2) + 4 * (lane >> 5);
        float sq = x2s[rowb] + yv - 2.0f * acc[ti][tj][r];
        float cc = sqrtf(fmaxf(sq, 0.0f) + 1e-6f);
        tile8[rowb * 128 + colb] = enc1_fp8(__expf(-0.1f * cc));
      }
    }
  __syncthreads();
#pragma unroll
  for (int p = 0; p < 4; ++p) {                      // coalesced 16B stores: 1024 chunks
    const int c = p * 256 + tid;                     // 128 rows x 8 chunks of 16B
    const int r = c >> 3, k = c & 7;
    *(uint4*)(E8 + (size_t)(i0 + r) * Mm + j0 + k * 16) = *(const uint4*)(tile8 + r * 128 + k * 16);
  }
}

// ---------- FAST row pass (fp8): 2 rows per wave ----------
__global__ __launch_bounds__(256) void row_pass8_kernel(
    const uint8_t* __restrict__ E8, const float* __restrict__ u, float* __restrict__ v) {
  const int wid  = (blockIdx.x * blockDim.x + threadIdx.x) >> 6;  // 0..4095
  const int lane = threadIdx.x & 63;
  const int r0   = wid * 2;
  const uint8_t* row = E8 + (size_t)r0 * Mm;
  float s0 = 0.0f, s1 = 0.0f;
#pragma unroll 1
  for (int g = 0; g < 8; g += 2) {                   // 2-group batches: 4 E loads + 8 u loads in flight
    const int ja = (g * 64 + lane) * 16;
    const int jb = ((g + 1) * 64 + lane) * 16;
    uint4 qa0 = *(const uint4*)(row + ja);
    uint4 qa1 = *(const uint4*)(row + (size_t)Mm + ja);
    uint4 qb0 = *(const uint4*)(row + jb);
    uint4 qb1 = *(const uint4*)(row + (size_t)Mm + jb);
    float4 uu[8];
#pragma unroll
    for (int i = 0; i < 4; ++i) uu[i]     = *(const float4*)(u + ja + i * 4);
#pragma unroll
    for (int i = 0; i < 4; ++i) uu[4 + i] = *(const float4*)(u + jb + i * 4);
    const uint32_t wa0[4] = {qa0.x, qa0.y, qa0.z, qa0.w};
    const uint32_t wa1[4] = {qa1.x, qa1.y, qa1.z, qa1.w};
    const uint32_t wb0[4] = {qb0.x, qb0.y, qb0.z, qb0.w};
    const uint32_t wb1[4] = {qb1.x, qb1.y, qb1.z, qb1.w};
#pragma unroll
    for (int d = 0; d < 4; ++d) {
      float f0[4], f1[4];
      const float* up = (const float*)&uu[d];
      cvt4_fp8(wa0[d], f0); cvt4_fp8(wa1[d], f1);
#pragma unroll
      for (int i = 0; i < 4; ++i) { s0 = fmaf(f0[i], up[i], s0); s1 = fmaf(f1[i], up[i], s1); }
    }
#pragma unroll
    for (int d = 0; d < 4; ++d) {
      float f0[4], f1[4];
      const float* up = (const float*)&uu[4 + d];
      cvt4_fp8(wb0[d], f0); cvt4_fp8(wb1[d], f1);
#pragma unroll
      for (int i = 0; i < 4; ++i) { s0 = fmaf(f0[i], up[i], s0); s1 = fmaf(f1[i], up[i], s1); }
    }
  }
#pragma unroll
  for (int o = 32; o > 0; o >>= 1) { s0 += __shfl_down(s0, o); s1 += __shfl_down(s1, o); }
  if (lane == 0) *(float2*)(v + r0) = make_float2(INV_N_F / s0, INV_N_F / s1);
}

// ---------- FAST col pass (fp8): 16 cols/thread, 8-deep row batches ----------
__global__ __launch_bounds__(256) void col_pass8_kernel(
    const uint8_t* __restrict__ E8, const float* __restrict__ v, float* __restrict__ part) {
  const int c0 = blockIdx.x * 4096 + threadIdx.x * 16;
  const int r0 = blockIdx.y * 64;
  const uint8_t* base = E8 + (size_t)r0 * Mm + c0;
  float acc[16] = {};
#pragma unroll 1
  for (int rb = 0; rb < 64; rb += 8) {
    uint4 q[8];
#pragma unroll
    for (int r = 0; r < 8; ++r) q[r] = *(const uint4*)(base + (size_t)(rb + r) * Mm);
#pragma unroll
    for (int r = 0; r < 8; ++r) {
      const float vr = v[r0 + rb + r];               // wave-uniform -> scalar load
      const uint32_t wd[4] = {q[r].x, q[r].y, q[r].z, q[r].w};
#pragma unroll
      for (int d = 0; d < 4; ++d) {
        float f[4]; cvt4_fp8(wd[d], f);
#pragma unroll
        for (int i = 0; i < 4; ++i) acc[d * 4 + i] = fmaf(f[i], vr, acc[d * 4 + i]);
      }
    }
  }
  float* dst = part + (size_t)blockIdx.y * Mm + c0;
#pragma unroll
  for (int d = 0; d < 4; ++d)
    *((float4*)dst + d) = make_float4(acc[d*4], acc[d*4+1], acc[d*4+2], acc[d*4+3]);
}

// ---------- combine: u_j = (1/m) / sum_chunks part ----------
__global__ __launch_bounds__(256) void combine_kernel(
    const float* __restrict__ part, float* __restrict__ u) {
  const int j = blockIdx.x * blockDim.x + threadIdx.x;
  float t = 0.0f;
#pragma unroll 8
  for (int c = 0; c < 128; ++c) t += part[(size_t)c * Mm + j];
  u[j] = INV_N_F / t;
}

// ---------- FAST final: recompute C via MFMA; pi = v*exp(-C/10)*u; cost += pi*C ----------
__global__ __launch_bounds__(256) void final_mfma(
    const h16* __restrict__ Xh, const h16* __restrict__ Yh,
    const float* __restrict__ x2, const float* __restrict__ y2,
    const float* __restrict__ v, const float* __restrict__ u,
    float* __restrict__ pi, float* __restrict__ cost) {
  __shared__ h16 smem[16384];
  __shared__ float x2s[128], y2s[128], vs[128], us[128];
  const int tid = threadIdx.x;
  const int i0 = blockIdx.y * 128, j0 = blockIdx.x * 128;
  if (tid < 128) { x2s[tid] = x2[i0 + tid]; vs[tid] = v[i0 + tid]; }
  else           { y2s[tid - 128] = y2[j0 + tid - 128]; us[tid - 128] = u[j0 + tid - 128]; }

  f32x16 acc[2][2];
#pragma unroll
  for (int a = 0; a < 2; ++a)
#pragma unroll
    for (int b = 0; b < 2; ++b)
#pragma unroll
      for (int r = 0; r < 16; ++r) acc[a][b][r] = 0.0f;

  const int w = tid >> 6, lane = tid & 63;
  const int mt0 = (w >> 1) * 2, nt0 = (w & 1) * 2;

  for (int kc = 0; kc < 4; ++kc) {
    __syncthreads();
#pragma unroll
    for (int p = 0; p < 4; ++p) {
      const int c  = p * 256 + tid;
      const int r  = c >> 3, k8 = c & 7;
      const int mt = r >> 5, m = r & 31, s = k8 >> 1, hf = k8 & 1;
      const int dst = ((mt * 4 + s) * 64 + m + 32 * hf) * 8;
      *(uint4*)(smem + dst)        = *(const uint4*)(Xh + (size_t)(i0 + r) * Kd + kc * 64 + k8 * 8);
      *(uint4*)(smem + 8192 + dst) = *(const uint4*)(Yh + (size_t)(j0 + r) * Kd + kc * 64 + k8 * 8);
    }
    __syncthreads();
#pragma unroll
    for (int s = 0; s < 4; ++s) {
      f16x8 a0 = *(const f16x8*)(smem + (((mt0    ) * 4 + s) * 64 + lane) * 8);
      f16x8 a1 = *(const f16x8*)(smem + (((mt0 + 1) * 4 + s) * 64 + lane) * 8);
      f16x8 b0 = *(const f16x8*)(smem + 8192 + (((nt0    ) * 4 + s) * 64 + lane) * 8);
      f16x8 b1 = *(const f16x8*)(smem + 8192 + (((nt0 + 1) * 4 + s) * 64 + lane) * 8);
      acc[0][0] = __builtin_amdgcn_mfma_f32_32x32x16_f16(a0, b0, acc[0][0], 0, 0, 0);
      acc[0][1] = __builtin_amdgcn_mfma_f32_32x32x16_f16(a0, b1, acc[0][1], 0, 0, 0);
      acc[1][0] = __builtin_amdgcn_mfma_f32_32x32x16_f16(a1, b0, acc[1][0], 0, 0, 0);
      acc[1][1] = __builtin_amdgcn_mfma_f32_32x32x16_f16(a1, b1, acc[1][1], 0, 0, 0);
    }
  }

  const int mq = (w >> 1) * 64, nq = (w & 1) * 64;
  float csum = 0.0f;
#pragma unroll
  for (int ti = 0; ti < 2; ++ti)
#pragma unroll
    for (int tj = 0; tj < 2; ++tj) {
      const int colb = nq + tj * 32 + (lane & 31);
      const float yv = y2s[colb], uu = us[colb];
#pragma unroll
      for (int r = 0; r < 16; ++r) {
        const int rowb = mq + ti * 32 + (r & 3) + 8 * (r >> 2) + 4 * (lane >> 5);
        float sq = x2s[rowb] + yv - 2.0f * acc[ti][tj][r];
        float cc = sqrtf(fmaxf(sq, 0.0f) + 1e-6f);
        float p  = vs[rowb] * __expf(-0.1f * cc) * uu;
        pi[(size_t)(i0 + rowb) * Mm + j0 + colb] = p;    // 128B segments per half-wave
        csum = fmaf(p, cc, csum);
      }
    }
#pragma unroll
  for (int o = 32; o > 0; o >>= 1) csum += __shfl_down(csum, o);
  if (lane == 0) atomicAdd(cost, csum);
}

// ================= fp32 fallback path (ws too small), unchanged ==================
template <typename ET>
__global__ __launch_bounds__(256) void build_e_f32(
    const float* __restrict__ X, const float* __restrict__ Y,
    const float* __restrict__ x2, const float* __restrict__ y2,
    ET* __restrict__ E) {
  __shared__ float As[64][66];
  __shared__ float Bs[64][66];
  const int tid = threadIdx.x;
  const int tx = tid & 15;
  const int ty = tid >> 4;
  const int i0 = blockIdx.y * 64;
  const int j0 = blockIdx.x * 64;
  float acc[4][4] = {};
  for (int k0 = 0; k0 < Kd; k0 += 64) {
    __syncthreads();
#pragma unroll
    for (int rep = 0; rep < 16; ++rep) {
      const int e = rep * 256 + tid;
      const int k = e & 63, i = e >> 6;
      As[k][i] = X[(size_t)(i0 + i) * Kd + k0 + k];
      Bs[k][i] = Y[(size_t)(j0 + i) * Kd + k0 + k];
    }
    __syncthreads();
    for (int k = 0; k < 64; ++k) {
      float a0 = As[k][ty*4+0], a1 = As[k][ty*4+1], a2 = As[k][ty*4+2], a3 = As[k][ty*4+3];
      float b0 = Bs[k][tx*4+0], b1 = Bs[k][tx*4+1], b2 = Bs[k][tx*4+2], b3 = Bs[k][tx*4+3];
      acc[0][0] += a0*b0; acc[0][1] += a0*b1; acc[0][2] += a0*b2; acc[0][3] += a0*b3;
      acc[1][0] += a1*b0; acc[1][1] += a1*b1; acc[1][2] += a1*b2; acc[1][3] += a1*b3;
      acc[2][0] += a2*b0; acc[2][1] += a2*b1; acc[2][2] += a2*b2; acc[2][3] += a2*b3;
      acc[3][0] += a3*b0; acc[3][1] += a3*b1; acc[3][2] += a3*b2; acc[3][3] += a3*b3;
    }
  }
  float xx[4], yy[4];
#pragma unroll
  for (int d = 0; d < 4; ++d) { xx[d] = x2[i0 + ty*4 + d]; yy[d] = y2[j0 + tx*4 + d]; }
#pragma unroll
  for (int di = 0; di < 4; ++di) {
    float e4[4];
#pragma unroll
    for (int dj = 0; dj < 4; ++dj) {
      float sq = xx[di] + yy[dj] - 2.0f * acc[di][dj];
      float c  = sqrtf(fmaxf(sq, 0.0f) + 1e-6f);
      e4[dj] = __expf(-c * 0.1f);
    }
    store4e(&E[(size_t)(i0 + ty*4 + di) * Mm + j0 + tx*4], e4[0], e4[1], e4[2], e4[3]);
  }
}

template <typename ET>
__global__ __launch_bounds__(256) void row_pass_kernel(
    const ET* __restrict__ E, const float* __restrict__ u, float* __restrict__ v) {
  const int wid  = (blockIdx.x * blockDim.x + threadIdx.x) >> 6;
  const int lane = threadIdx.x & 63;
  const ET* row = E + (size_t)wid * Mm;
  float s = 0.0f;
#pragma unroll 4
  for (int g = 0; g < 16; ++g) {
    const int j8 = (g * 64 + lane) * 8;
    float ev[8]; load8(row + j8, ev);
    const float4 u0 = *(const float4*)(u + j8);
    const float4 u1 = *(const float4*)(u + j8 + 4);
    s += ev[0]*u0.x + ev[1]*u0.y + ev[2]*u0.z + ev[3]*u0.w;
    s += ev[4]*u1.x + ev[5]*u1.y + ev[6]*u1.z + ev[7]*u1.w;
  }
#pragma unroll
  for (int o = 32; o > 0; o >>= 1) s += __shfl_down(s, o);
  if (lane == 0) v[wid] = INV_N_F / s;
}

template <typename ET>
__global__ __launch_bounds__(256) void col_pass_kernel(
    const ET* __restrict__ E, const float* __restrict__ v, float* __restrict__ part) {
  const int c0 = blockIdx.x * 2048 + threadIdx.x * 8;
  const int r0 = blockIdx.y * 64;
  float acc[8] = {};
#pragma unroll 4
  for (int r = r0; r < r0 + 64; ++r) {
    const float vr = v[r];
    float ev[8]; load8(E + (size_t)r * Mm + c0, ev);
#pragma unroll
    for (int c = 0; c < 8; ++c) acc[c] += ev[c] * vr;
  }
  float* dst = part + (size_t)blockIdx.y * Mm + c0;
  *(float4*)dst       = make_float4(acc[0], acc[1], acc[2], acc[3]);
  *((float4*)dst + 1) = make_float4(acc[4], acc[5], acc[6], acc[7]);
}

template <typename ET>
__global__ __launch_bounds__(256) void final_pass_kernel(
    const ET* E, const float* __restrict__ v, const float* __restrict__ u,
    float* pi, float* cost) {            // E/pi alias in fallback -> no restrict
  const int wid  = (blockIdx.x * blockDim.x + threadIdx.x) >> 6;
  const int lane = threadIdx.x & 63;
  const ET* row = E + (size_t)wid * Mm;
  float* prow = pi + (size_t)wid * Mm;
  const float vi = v[wid];
  float csum = 0.0f;
  for (int g = 0; g < 16; ++g) {
    const int j8 = (g * 64 + lane) * 8;
    float ev[8]; load8(row + j8, ev);
#pragma unroll
    for (int c = 0; c < 8; ++c) {
      const float uu  = u[j8 + c];
      const float p   = vi * ev[c] * uu;
      const float Cij = -LAM_F * __logf(ev[c]);
      prow[j8 + c] = p;
      csum += p * Cij;
    }
  }
#pragma unroll
  for (int o = 32; o > 0; o >>= 1) csum += __shfl_down(csum, o);
  if (lane == 0) atomicAdd(cost, csum);
}

// ---------- host ----------
extern "C" void kernel_launch(void* const* d_in, const int* in_sizes, int n_in,
                              void* d_out, int out_size, void* d_ws, size_t ws_size,
                              hipStream_t stream) {
  const float* X = (const float*)d_in[0];
  const float* Y = (const float*)d_in[1];
  float* out  = (float*)d_out;
  float* cost = out;
  float* pi   = out + 1;

  char*  ws   = (char*)d_ws;
  float* x2   = (float*)ws;
  float* y2   = x2 + Nn;
  float* u    = y2 + Mm;
  float* v    = u + Mm;
  float* part = v + Nn;                                   // 128 x 8192 f32 = 4 MB
  h16*   XhW  = (h16*)(part + (size_t)128 * Mm);          // fp16 X copy (4 MB) - fast path
  h16*   YhW  = XhW + (size_t)Nn * Kd;                    // fp16 Y copy (4 MB)
  const size_t pre_bytes = (size_t)((char*)(YhW + (size_t)Mm * Kd) - ws);
  const size_t e_off = (pre_bytes + 255) & ~(size_t)255;
  const bool fast = ws_size >= e_off + (size_t)Nn * Mm + 256;   // + 64 MB fp8 E

  // Xh/Yh live in ws on fast path (final_mfma reads them while writing pi);
  // fallback parks them in the pi region (never read there).
  h16* Xh = fast ? XhW : (h16*)(((uintptr_t)pi + 15) & ~(uintptr_t)15);
  h16* Yh = Xh + (size_t)Nn * Kd;

  setup_kernel<<<4096, 256, 0, stream>>>(X, Y, x2, y2, u, cost, Xh, Yh);

  if (fast) {
    uint8_t* E8 = (uint8_t*)ws + e_off;                   // fp8 K (64 MB, L3-resident)
    build_e8_mfma<<<dim3(64, 64), 256, 0, stream>>>(Xh, Yh, x2, y2, E8);
    for (int it = 0; it < 50; ++it) {
      row_pass8_kernel<<<1024, 256, 0, stream>>>(E8, u, v);
      col_pass8_kernel<<<dim3(2, 128), 256, 0, stream>>>(E8, v, part);
      combine_kernel<<<32, 256, 0, stream>>>(part, u);
    }
    final_mfma<<<dim3(64, 64), 256, 0, stream>>>(Xh, Yh, x2, y2, v, u, pi, cost);
  } else {
    float* E = pi;                                        // fallback: fp32 K parked in pi slot
    build_e_f32<float><<<dim3(128, 128), 256, 0, stream>>>(X, Y, x2, y2, E);
    for (int it = 0; it < 50; ++it) {
      row_pass_kernel<float><<<2048, 256, 0, stream>>>(E, u, v);
      col_pass_kernel<float><<<dim3(4, 128), 256, 0, stream>>>(E, v, part);
      combine_kernel<<<32, 256, 0, stream>>>(part, u);
    }
    final_pass_kernel<float><<<2048, 256, 0, stream>>>(E, v, u, pi, cost);  // in-place
  }
}

// Round 6
// 2151.519 us; speedup vs baseline: 2.5452x; 1.0318x over previous
//
#include <hip/hip_runtime.h>
#include <cstdint>
#include <cstddef>

static constexpr int Nn = 8192;   // rows of X
static constexpr int Mm = 8192;   // rows of Y
static constexpr int Kd = 256;    // feature dim
static constexpr float LAM_F   = 10.0f;
static constexpr float INV_N_F = 1.0f / 8192.0f;

typedef _Float16 h16;
typedef _Float16 h16x4 __attribute__((ext_vector_type(4)));
typedef _Float16 f16x8 __attribute__((ext_vector_type(8)));
typedef float    f32x16 __attribute__((ext_vector_type(16)));

// ---------- fp8 e4m3 helpers (HW cvt on gfx950; manual RNE fallback) ----------
__device__ __forceinline__ float dec1_fp8(uint32_t b) {      // fallback decode (positive, finite)
  uint32_t e = (b >> 3) & 15u, m = b & 7u;
  float n = __uint_as_float(((e + 120u) << 23) | (m << 20)); // normal
  float s = (float)m * 0.001953125f;                         // subnormal: m * 2^-9
  return e ? n : s;
}
__device__ __forceinline__ void cvt4_fp8(uint32_t w, float* o) {
#if __has_builtin(__builtin_amdgcn_cvt_pk_f32_fp8)
  auto lo = __builtin_amdgcn_cvt_pk_f32_fp8(w, false);
  auto hi = __builtin_amdgcn_cvt_pk_f32_fp8(w, true);
  o[0] = lo[0]; o[1] = lo[1]; o[2] = hi[0]; o[3] = hi[1];
#else
  o[0] = dec1_fp8(w & 255u); o[1] = dec1_fp8((w >> 8) & 255u);
  o[2] = dec1_fp8((w >> 16) & 255u); o[3] = dec1_fp8(w >> 24);
#endif
}
__device__ __forceinline__ uint8_t enc1_fp8(float x) {       // x in (0,1]
#if __has_builtin(__builtin_amdgcn_cvt_pk_fp8_f32)
  return (uint8_t)(__builtin_amdgcn_cvt_pk_fp8_f32(x, x, 0, false) & 0xff);
#else
  uint32_t b = __float_as_uint(x);
  int e = (int)((b >> 23) & 255) - 127;
  uint32_t m = b & 0x7fffffu;
  if (e < -9) return 0;
  if (e >= -6) {                                             // normal, RNE on 3-bit mantissa
    uint32_t keep = m >> 20, rest = m & 0xfffffu;
    if (rest > 0x80000u || (rest == 0x80000u && (keep & 1u))) keep++;
    return (uint8_t)(((uint32_t)(e + 7) << 3) + keep);       // carry rolls into exponent
  }
  return (uint8_t)(int)(x * 512.0f + 0.5f);                  // subnormal
#endif
}

// ---------- staging slot swizzle (kills 8-way ds_write bank conflict) ----------
// logical chunk (tile mt, row m, k8) -> slot (mt*4+s)*64 + hf*32 + (m^k8),
// s=k8>>1, hf=k8&1.  Write side: 8 lanes sharing m get distinct slot%8.
// Read side (k-step s, lane l wants m=l&31, k8=2s+(l>>5)):
__device__ __forceinline__ int frag_slot(int t, int s, int l) {
  return (t * 4 + s) * 64 + (l & 32) + ((l & 31) ^ (2 * s + (l >> 5)));
}

// ---------- load helpers for fp32 fallback path ----------
__device__ __forceinline__ void load8(const float* p, float* o) {
#pragma unroll
  for (int i = 0; i < 8; ++i) o[i] = p[i];
}
__device__ __forceinline__ void store4e(float* p, float a, float b, float c, float d) {
  p[0] = a; p[1] = b; p[2] = c; p[3] = d;
}

// ---------- setup: row norms, u=1, cost=0, fp16 copies of X,Y ----------
__global__ __launch_bounds__(256) void setup_kernel(
    const float* __restrict__ X, const float* __restrict__ Y,
    float* __restrict__ x2, float* __restrict__ y2,
    float* __restrict__ u, float* __restrict__ cost,
    h16* __restrict__ Xh, h16* __restrict__ Yh) {
  const int gid  = blockIdx.x * blockDim.x + threadIdx.x;
  const int wid  = gid >> 6;          // 0..16383 : one wave per row
  const int lane = threadIdx.x & 63;
  const bool isX = wid < Nn;
  const int row  = isX ? wid : wid - Nn;
  const float4* rp = (const float4*)((isX ? X : Y) + (size_t)row * Kd);
  float4 q = rp[lane];                // 64 lanes x float4 = 256 floats
  h16x4 hq; hq[0] = (h16)q.x; hq[1] = (h16)q.y; hq[2] = (h16)q.z; hq[3] = (h16)q.w;
  *(h16x4*)((isX ? Xh : Yh) + (size_t)row * Kd + lane * 4) = hq;
  float s = q.x*q.x + q.y*q.y + q.z*q.z + q.w*q.w;
#pragma unroll
  for (int o = 32; o > 0; o >>= 1) s += __shfl_down(s, o);
  if (lane == 0) { if (isX) x2[row] = s; else y2[row] = s; }
  if (gid < Mm) u[gid] = 1.0f;        // g0 = 0  ->  u0 = 1
  if (gid == 0) cost[0] = 0.0f;
}

// ---------- build K = exp(-C/LAM) as fp8 e4m3 via MFMA f16, 128x128 tile ----------
__global__ __launch_bounds__(256) void build_e8_mfma(
    const h16* __restrict__ Xh, const h16* __restrict__ Yh,
    const float* __restrict__ x2, const float* __restrict__ y2,
    uint8_t* __restrict__ E8) {
  __shared__ h16 smem[16384];         // 32 KB: A/B staging; epilogue reuses first 16 KB as fp8 tile
  __shared__ float x2s[128], y2s[128];
  const int tid = threadIdx.x;
  const int i0 = blockIdx.y * 128, j0 = blockIdx.x * 128;
  if (tid < 128) x2s[tid] = x2[i0 + tid];
  else           y2s[tid - 128] = y2[j0 + tid - 128];

  f32x16 acc[2][2];
#pragma unroll
  for (int a = 0; a < 2; ++a)
#pragma unroll
    for (int b = 0; b < 2; ++b)
#pragma unroll
      for (int r = 0; r < 16; ++r) acc[a][b][r] = 0.0f;

  const int w = tid >> 6, lane = tid & 63;
  const int mt0 = (w >> 1) * 2, nt0 = (w & 1) * 2;

  for (int kc = 0; kc < 4; ++kc) {                   // K = 256 in 4 chunks of 64
    __syncthreads();
#pragma unroll
    for (int p = 0; p < 4; ++p) {                    // stage 128 rows x 64 k (A and B), swizzled
      const int c  = p * 256 + tid;
      const int r  = c >> 3, k8 = c & 7;
      const int mt = r >> 5, m = r & 31, s = k8 >> 1, hf = k8 & 1;
      const int slot = (mt * 4 + s) * 64 + hf * 32 + (m ^ k8);
      *(uint4*)(smem + slot * 8)        = *(const uint4*)(Xh + (size_t)(i0 + r) * Kd + kc * 64 + k8 * 8);
      *(uint4*)(smem + 8192 + slot * 8) = *(const uint4*)(Yh + (size_t)(j0 + r) * Kd + kc * 64 + k8 * 8);
    }
    __syncthreads();
#pragma unroll
    for (int s = 0; s < 4; ++s) {                    // 4 k-steps of 16
      f16x8 a0 = *(const f16x8*)(smem + frag_slot(mt0,     s, lane) * 8);
      f16x8 a1 = *(const f16x8*)(smem + frag_slot(mt0 + 1, s, lane) * 8);
      f16x8 b0 = *(const f16x8*)(smem + 8192 + frag_slot(nt0,     s, lane) * 8);
      f16x8 b1 = *(const f16x8*)(smem + 8192 + frag_slot(nt0 + 1, s, lane) * 8);
      acc[0][0] = __builtin_amdgcn_mfma_f32_32x32x16_f16(a0, b0, acc[0][0], 0, 0, 0);
      acc[0][1] = __builtin_amdgcn_mfma_f32_32x32x16_f16(a0, b1, acc[0][1], 0, 0, 0);
      acc[1][0] = __builtin_amdgcn_mfma_f32_32x32x16_f16(a1, b0, acc[1][0], 0, 0, 0);
      acc[1][1] = __builtin_amdgcn_mfma_f32_32x32x16_f16(a1, b1, acc[1][1], 0, 0, 0);
    }
  }

  __syncthreads();                                   // all waves done reading A/B
  uint8_t* tile8 = (uint8_t*)smem;                   // 128x128 fp8 tile (16 KB)
  const int mq = (w >> 1) * 64, nq = (w & 1) * 64;
#pragma unroll
  for (int ti = 0; ti < 2; ++ti)
#pragma unroll
    for (int tj = 0; tj < 2; ++tj) {
      const int colb = nq + tj * 32 + (lane & 31);
      const float yv = y2s[colb];
#pragma unroll
      for (int r = 0; r < 16; ++r) {
        // 32x32 C/D layout: col = lane&31, row = (r&3) + 8*(r>>2) + 4*(lane>>5)
        const int rowb = mq + ti * 32 + (r & 3) + 8 * (r >> 2) + 4 * (lane >> 5);
        float sq = x2s[rowb] + yv - 2.0f * acc[ti][tj][r];
        float cc = sqrtf(fmaxf(sq, 0.0f) + 1e-6f);
        tile8[rowb * 128 + colb] = enc1_fp8(__expf(-0.1f * cc));
      }
    }
  __syncthreads();
#pragma unroll
  for (int p = 0; p < 4; ++p) {                      // coalesced 16B stores: 1024 chunks
    const int c = p * 256 + tid;                     // 128 rows x 8 chunks of 16B
    const int r = c >> 3, k = c & 7;
    *(uint4*)(E8 + (size_t)(i0 + r) * Mm + j0 + k * 16) = *(const uint4*)(tile8 + r * 128 + k * 16);
  }
}

// ---------- FAST row pass (fp8): 2 rows per wave, u staged in LDS ----------
__global__ __launch_bounds__(256) void row_pass8_kernel(
    const uint8_t* __restrict__ E8, const float* __restrict__ u, float* __restrict__ v) {
  __shared__ float us[8192];                         // full u vector, 32 KB, shared by 4 waves
#pragma unroll
  for (int i = 0; i < 8; ++i) {
    const int o = (i * 256 + threadIdx.x) * 4;
    *(float4*)(us + o) = *(const float4*)(u + o);
  }
  __syncthreads();
  const int wid  = (blockIdx.x * blockDim.x + threadIdx.x) >> 6;  // 0..4095
  const int lane = threadIdx.x & 63;
  const int r0   = wid * 2;
  const uint8_t* row = E8 + (size_t)r0 * Mm;
  float s0 = 0.0f, s1 = 0.0f;
#pragma unroll 1
  for (int g = 0; g < 8; g += 2) {                   // 2-group batches: 4 E loads in flight
    const int ja = (g * 64 + lane) * 16;
    const int jb = ((g + 1) * 64 + lane) * 16;
    uint4 qa0 = *(const uint4*)(row + ja);
    uint4 qa1 = *(const uint4*)(row + (size_t)Mm + ja);
    uint4 qb0 = *(const uint4*)(row + jb);
    uint4 qb1 = *(const uint4*)(row + (size_t)Mm + jb);
    const uint32_t wa0[4] = {qa0.x, qa0.y, qa0.z, qa0.w};
    const uint32_t wa1[4] = {qa1.x, qa1.y, qa1.z, qa1.w};
    const uint32_t wb0[4] = {qb0.x, qb0.y, qb0.z, qb0.w};
    const uint32_t wb1[4] = {qb1.x, qb1.y, qb1.z, qb1.w};
#pragma unroll
    for (int d = 0; d < 4; ++d) {
      float f0[4], f1[4];
      const float4 uv = *(const float4*)(us + ja + d * 4);
      const float up[4] = {uv.x, uv.y, uv.z, uv.w};
      cvt4_fp8(wa0[d], f0); cvt4_fp8(wa1[d], f1);
#pragma unroll
      for (int i = 0; i < 4; ++i) { s0 = fmaf(f0[i], up[i], s0); s1 = fmaf(f1[i], up[i], s1); }
    }
#pragma unroll
    for (int d = 0; d < 4; ++d) {
      float f0[4], f1[4];
      const float4 uv = *(const float4*)(us + jb + d * 4);
      const float up[4] = {uv.x, uv.y, uv.z, uv.w};
      cvt4_fp8(wb0[d], f0); cvt4_fp8(wb1[d], f1);
#pragma unroll
      for (int i = 0; i < 4; ++i) { s0 = fmaf(f0[i], up[i], s0); s1 = fmaf(f1[i], up[i], s1); }
    }
  }
#pragma unroll
  for (int o = 32; o > 0; o >>= 1) { s0 += __shfl_down(s0, o); s1 += __shfl_down(s1, o); }
  if (lane == 0) *(float2*)(v + r0) = make_float2(INV_N_F / s0, INV_N_F / s1);
}

// ---------- FAST col pass (fp8): 16 cols/thread, 8-deep row batches ----------
__global__ __launch_bounds__(256) void col_pass8_kernel(
    const uint8_t* __restrict__ E8, const float* __restrict__ v, float* __restrict__ part) {
  const int c0 = blockIdx.x * 4096 + threadIdx.x * 16;
  const int r0 = blockIdx.y * 64;
  const uint8_t* base = E8 + (size_t)r0 * Mm + c0;
  float acc[16] = {};
#pragma unroll 1
  for (int rb = 0; rb < 64; rb += 8) {
    uint4 q[8];
#pragma unroll
    for (int r = 0; r < 8; ++r) q[r] = *(const uint4*)(base + (size_t)(rb + r) * Mm);
#pragma unroll
    for (int r = 0; r < 8; ++r) {
      const float vr = v[r0 + rb + r];               // wave-uniform -> scalar load
      const uint32_t wd[4] = {q[r].x, q[r].y, q[r].z, q[r].w};
#pragma unroll
      for (int d = 0; d < 4; ++d) {
        float f[4]; cvt4_fp8(wd[d], f);
#pragma unroll
        for (int i = 0; i < 4; ++i) acc[d * 4 + i] = fmaf(f[i], vr, acc[d * 4 + i]);
      }
    }
  }
  float* dst = part + (size_t)blockIdx.y * Mm + c0;
#pragma unroll
  for (int d = 0; d < 4; ++d)
    *((float4*)dst + d) = make_float4(acc[d*4], acc[d*4+1], acc[d*4+2], acc[d*4+3]);
}

// ---------- combine: u_j = (1/m) / sum_chunks part ----------
__global__ __launch_bounds__(256) void combine_kernel(
    const float* __restrict__ part, float* __restrict__ u) {
  const int j = blockIdx.x * blockDim.x + threadIdx.x;
  float t = 0.0f;
#pragma unroll 8
  for (int c = 0; c < 128; ++c) t += part[(size_t)c * Mm + j];
  u[j] = INV_N_F / t;
}

// ---------- FAST final: recompute C via MFMA; pi = v*exp(-C/10)*u; LDS-staged writes ----------
__global__ __launch_bounds__(256) void final_mfma(
    const h16* __restrict__ Xh, const h16* __restrict__ Yh,
    const float* __restrict__ x2, const float* __restrict__ y2,
    const float* __restrict__ v, const float* __restrict__ u,
    float* __restrict__ pi, float* __restrict__ cost) {
  __shared__ __align__(16) unsigned char smemraw[65536];   // staging (32 KB) / f32 out-tile (64 KB)
  h16*   smem = (h16*)smemraw;
  float* tile = (float*)smemraw;
  __shared__ float x2s[128], y2s[128], vs[128], us[128];
  const int tid = threadIdx.x;
  const int i0 = blockIdx.y * 128, j0 = blockIdx.x * 128;
  if (tid < 128) { x2s[tid] = x2[i0 + tid]; vs[tid] = v[i0 + tid]; }
  else           { y2s[tid - 128] = y2[j0 + tid - 128]; us[tid - 128] = u[j0 + tid - 128]; }

  f32x16 acc[2][2];
#pragma unroll
  for (int a = 0; a < 2; ++a)
#pragma unroll
    for (int b = 0; b < 2; ++b)
#pragma unroll
      for (int r = 0; r < 16; ++r) acc[a][b][r] = 0.0f;

  const int w = tid >> 6, lane = tid & 63;
  const int mt0 = (w >> 1) * 2, nt0 = (w & 1) * 2;

  for (int kc = 0; kc < 4; ++kc) {
    __syncthreads();
#pragma unroll
    for (int p = 0; p < 4; ++p) {                    // swizzled staging (conflict-free)
      const int c  = p * 256 + tid;
      const int r  = c >> 3, k8 = c & 7;
      const int mt = r >> 5, m = r & 31, s = k8 >> 1, hf = k8 & 1;
      const int slot = (mt * 4 + s) * 64 + hf * 32 + (m ^ k8);
      *(uint4*)(smem + slot * 8)        = *(const uint4*)(Xh + (size_t)(i0 + r) * Kd + kc * 64 + k8 * 8);
      *(uint4*)(smem + 8192 + slot * 8) = *(const uint4*)(Yh + (size_t)(j0 + r) * Kd + kc * 64 + k8 * 8);
    }
    __syncthreads();
#pragma unroll
    for (int s = 0; s < 4; ++s) {
      f16x8 a0 = *(const f16x8*)(smem + frag_slot(mt0,     s, lane) * 8);
      f16x8 a1 = *(const f16x8*)(smem + frag_slot(mt0 + 1, s, lane) * 8);
      f16x8 b0 = *(const f16x8*)(smem + 8192 + frag_slot(nt0,     s, lane) * 8);
      f16x8 b1 = *(const f16x8*)(smem + 8192 + frag_slot(nt0 + 1, s, lane) * 8);
      acc[0][0] = __builtin_amdgcn_mfma_f32_32x32x16_f16(a0, b0, acc[0][0], 0, 0, 0);
      acc[0][1] = __builtin_amdgcn_mfma_f32_32x32x16_f16(a0, b1, acc[0][1], 0, 0, 0);
      acc[1][0] = __builtin_amdgcn_mfma_f32_32x32x16_f16(a1, b0, acc[1][0], 0, 0, 0);
      acc[1][1] = __builtin_amdgcn_mfma_f32_32x32x16_f16(a1, b1, acc[1][1], 0, 0, 0);
    }
  }

  __syncthreads();                                   // all waves done reading A/B staging
  const int mq = (w >> 1) * 64, nq = (w & 1) * 64;
  float csum = 0.0f;
#pragma unroll
  for (int ti = 0; ti < 2; ++ti)
#pragma unroll
    for (int tj = 0; tj < 2; ++tj) {
      const int colb = nq + tj * 32 + (lane & 31);
      const float yv = y2s[colb], uu = us[colb];
#pragma unroll
      for (int r = 0; r < 16; ++r) {
        const int rowb = mq + ti * 32 + (r & 3) + 8 * (r >> 2) + 4 * (lane >> 5);
        float sq = x2s[rowb] + yv - 2.0f * acc[ti][tj][r];
        float cc = sqrtf(fmaxf(sq, 0.0f) + 1e-6f);
        float p  = vs[rowb] * __expf(-0.1f * cc) * uu;
        tile[rowb * 128 + colb] = p;                 // bank = colb%32 -> conflict-free
        csum = fmaf(p, cc, csum);
      }
    }
  __syncthreads();
#pragma unroll
  for (int it2 = 0; it2 < 16; ++it2) {               // coalesced: full-wave 1KB runs (2 rows x 512B)
    const int c = it2 * 256 + tid;                   // 4096 chunks of 16 B
    const int r = c >> 5, k = c & 31;
    *(uint4*)(pi + (size_t)(i0 + r) * Mm + j0 + k * 4) = *(const uint4*)(tile + r * 128 + k * 4);
  }
#pragma unroll
  for (int o = 32; o > 0; o >>= 1) csum += __shfl_down(csum, o);
  if (lane == 0) atomicAdd(cost, csum);
}

// ================= fp32 fallback path (ws too small), unchanged ==================
template <typename ET>
__global__ __launch_bounds__(256) void build_e_f32(
    const float* __restrict__ X, const float* __restrict__ Y,
    const float* __restrict__ x2, const float* __restrict__ y2,
    ET* __restrict__ E) {
  __shared__ float As[64][66];
  __shared__ float Bs[64][66];
  const int tid = threadIdx.x;
  const int tx = tid & 15;
  const int ty = tid >> 4;
  const int i0 = blockIdx.y * 64;
  const int j0 = blockIdx.x * 64;
  float acc[4][4] = {};
  for (int k0 = 0; k0 < Kd; k0 += 64) {
    __syncthreads();
#pragma unroll
    for (int rep = 0; rep < 16; ++rep) {
      const int e = rep * 256 + tid;
      const int k = e & 63, i = e >> 6;
      As[k][i] = X[(size_t)(i0 + i) * Kd + k0 + k];
      Bs[k][i] = Y[(size_t)(j0 + i) * Kd + k0 + k];
    }
    __syncthreads();
    for (int k = 0; k < 64; ++k) {
      float a0 = As[k][ty*4+0], a1 = As[k][ty*4+1], a2 = As[k][ty*4+2], a3 = As[k][ty*4+3];
      float b0 = Bs[k][tx*4+0], b1 = Bs[k][tx*4+1], b2 = Bs[k][tx*4+2], b3 = Bs[k][tx*4+3];
      acc[0][0] += a0*b0; acc[0][1] += a0*b1; acc[0][2] += a0*b2; acc[0][3] += a0*b3;
      acc[1][0] += a1*b0; acc[1][1] += a1*b1; acc[1][2] += a1*b2; acc[1][3] += a1*b3;
      acc[2][0] += a2*b0; acc[2][1] += a2*b1; acc[2][2] += a2*b2; acc[2][3] += a2*b3;
      acc[3][0] += a3*b0; acc[3][1] += a3*b1; acc[3][2] += a3*b2; acc[3][3] += a3*b3;
    }
  }
  float xx[4], yy[4];
#pragma unroll
  for (int d = 0; d < 4; ++d) { xx[d] = x2[i0 + ty*4 + d]; yy[d] = y2[j0 + tx*4 + d]; }
#pragma unroll
  for (int di = 0; di < 4; ++di) {
    float e4[4];
#pragma unroll
    for (int dj = 0; dj < 4; ++dj) {
      float sq = xx[di] + yy[dj] - 2.0f * acc[di][dj];
      float c  = sqrtf(fmaxf(sq, 0.0f) + 1e-6f);
      e4[dj] = __expf(-c * 0.1f);
    }
    store4e(&E[(size_t)(i0 + ty*4 + di) * Mm + j0 + tx*4], e4[0], e4[1], e4[2], e4[3]);
  }
}

template <typename ET>
__global__ __launch_bounds__(256) void row_pass_kernel(
    const ET* __restrict__ E, const float* __restrict__ u, float* __restrict__ v) {
  const int wid  = (blockIdx.x * blockDim.x + threadIdx.x) >> 6;
  const int lane = threadIdx.x & 63;
  const ET* row = E + (size_t)wid * Mm;
  float s = 0.0f;
#pragma unroll 4
  for (int g = 0; g < 16; ++g) {
    const int j8 = (g * 64 + lane) * 8;
    float ev[8]; load8(row + j8, ev);
    const float4 u0 = *(const float4*)(u + j8);
    const float4 u1 = *(const float4*)(u + j8 + 4);
    s += ev[0]*u0.x + ev[1]*u0.y + ev[2]*u0.z + ev[3]*u0.w;
    s += ev[4]*u1.x + ev[5]*u1.y + ev[6]*u1.z + ev[7]*u1.w;
  }
#pragma unroll
  for (int o = 32; o > 0; o >>= 1) s += __shfl_down(s, o);
  if (lane == 0) v[wid] = INV_N_F / s;
}

template <typename ET>
__global__ __launch_bounds__(256) void col_pass_kernel(
    const ET* __restrict__ E, const float* __restrict__ v, float* __restrict__ part) {
  const int c0 = blockIdx.x * 2048 + threadIdx.x * 8;
  const int r0 = blockIdx.y * 64;
  float acc[8] = {};
#pragma unroll 4
  for (int r = r0; r < r0 + 64; ++r) {
    const float vr = v[r];
    float ev[8]; load8(E + (size_t)r * Mm + c0, ev);
#pragma unroll
    for (int c = 0; c < 8; ++c) acc[c] += ev[c] * vr;
  }
  float* dst = part + (size_t)blockIdx.y * Mm + c0;
  *(float4*)dst       = make_float4(acc[0], acc[1], acc[2], acc[3]);
  *((float4*)dst + 1) = make_float4(acc[4], acc[5], acc[6], acc[7]);
}

template <typename ET>
__global__ __launch_bounds__(256) void final_pass_kernel(
    const ET* E, const float* __restrict__ v, const float* __restrict__ u,
    float* pi, float* cost) {            // E/pi alias in fallback -> no restrict
  const int wid  = (blockIdx.x * blockDim.x + threadIdx.x) >> 6;
  const int lane = threadIdx.x & 63;
  const ET* row = E + (size_t)wid * Mm;
  float* prow = pi + (size_t)wid * Mm;
  const float vi = v[wid];
  float csum = 0.0f;
  for (int g = 0; g < 16; ++g) {
    const int j8 = (g * 64 + lane) * 8;
    float ev[8]; load8(row + j8, ev);
#pragma unroll
    for (int c = 0; c < 8; ++c) {
      const float uu  = u[j8 + c];
      const float p   = vi * ev[c] * uu;
      const float Cij = -LAM_F * __logf(ev[c]);
      prow[j8 + c] = p;
      csum += p * Cij;
    }
  }
#pragma unroll
  for (int o = 32; o > 0; o >>= 1) csum += __shfl_down(csum, o);
  if (lane == 0) atomicAdd(cost, csum);
}

// ---------- host ----------
extern "C" void kernel_launch(void* const* d_in, const int* in_sizes, int n_in,
                              void* d_out, int out_size, void* d_ws, size_t ws_size,
                              hipStream_t stream) {
  const float* X = (const float*)d_in[0];
  const float* Y = (const float*)d_in[1];
  float* out  = (float*)d_out;
  float* cost = out;
  float* pi   = out + 1;

  char*  ws   = (char*)d_ws;
  float* x2   = (float*)ws;
  float* y2   = x2 + Nn;
  float* u    = y2 + Mm;
  float* v    = u + Mm;
  float* part = v + Nn;                                   // 128 x 8192 f32 = 4 MB
  h16*   XhW  = (h16*)(part + (size_t)128 * Mm);          // fp16 X copy (4 MB) - fast path
  h16*   YhW  = XhW + (size_t)Nn * Kd;                    // fp16 Y copy (4 MB)
  const size_t pre_bytes = (size_t)((char*)(YhW + (size_t)Mm * Kd) - ws);
  const size_t e_off = (pre_bytes + 255) & ~(size_t)255;
  const bool fast = ws_size >= e_off + (size_t)Nn * Mm + 256;   // + 64 MB fp8 E

  // Xh/Yh live in ws on fast path (final_mfma reads them while writing pi);
  // fallback parks them in the pi region (never read there).
  h16* Xh = fast ? XhW : (h16*)(((uintptr_t)pi + 15) & ~(uintptr_t)15);
  h16* Yh = Xh + (size_t)Nn * Kd;

  setup_kernel<<<4096, 256, 0, stream>>>(X, Y, x2, y2, u, cost, Xh, Yh);

  if (fast) {
    uint8_t* E8 = (uint8_t*)ws + e_off;                   // fp8 K (64 MB, L3-resident)
    build_e8_mfma<<<dim3(64, 64), 256, 0, stream>>>(Xh, Yh, x2, y2, E8);
    for (int it = 0; it < 50; ++it) {
      row_pass8_kernel<<<1024, 256, 0, stream>>>(E8, u, v);
      col_pass8_kernel<<<dim3(2, 128), 256, 0, stream>>>(E8, v, part);
      combine_kernel<<<32, 256, 0, stream>>>(part, u);
    }
    final_mfma<<<dim3(64, 64), 256, 0, stream>>>(Xh, Yh, x2, y2, v, u, pi, cost);
  } else {
    float* E = pi;                                        // fallback: fp32 K parked in pi slot
    build_e_f32<float><<<dim3(128, 128), 256, 0, stream>>>(X, Y, x2, y2, E);
    for (int it = 0; it < 50; ++it) {
      row_pass_kernel<float><<<2048, 256, 0, stream>>>(E, u, v);
      col_pass_kernel<float><<<dim3(4, 128), 256, 0, stream>>>(E, v, part);
      combine_kernel<<<32, 256, 0, stream>>>(part, u);
    }
    final_pass_kernel<float><<<2048, 256, 0, stream>>>(E, v, u, pi, cost);  // in-place
  }
}